// Round 9
// baseline (449.182 us; speedup 1.0000x reference)
//
#include <hip/hip_runtime.h>
#include <hip/hip_bf16.h>

// EGNN encoder, N=50000, E=250000, D=128, L=4. bf16 inputs/output (verified R2).
// R3: CSR-by-tgt aggregation.  R4: 3-stage CSR scan.  R5: agg chunked x4.
// R7: weight-stationary streaming matmuls.  R10: bf16 residual stream.
// R11: merged setup kernel. 524us.
// R12 FAILED: cooperative front-end (+350us, occupancy-starved).
// R13 FAILED: 512-thr mm blocks (scattered-2B store amplification exposed).
// R14: fragment-swizzled internal tensors (agg regressed). 563us.
// R15: split layouts per consumer; mm C-tiles staged through per-wave LDS. 518us.
// R16/R17 FAILED: weights from L1/L2 -> write-streams evict weights from L2.
//     LESSON: weight reuse must live in LDS.
// R18: mm_ab -> 2x mm_single (3 blocks/CU); mm_hidden+mm_res fused into mega
//     (h stays on-chip). 459us.
// R19: agg packed-scalar phase + persistent waves. 446.6us. Post-mortem: the
//     butterfly (48 VALU ops/4-edge chunk), not trans, is agg's largest block.
// R20: agg folded butterfly (keep/send by own lane bit per xor step: 96->28 ops
//     per 8 edges, all compile-time indices) + 8-edge chunks (half the loop
//     iterations at avg degree 5, 8-deep gather ILP).

#define NNODES 50000
#define NEDGES 250000
#define NTILES 3125   // 50000/16 exactly, no tail
#define SGRID  768    // mm_single: 768 blocks x 4 waves, 3 blocks/CU co-resident
#define MGRID  256    // mega: 256 blocks x 8 waves, 1 block/CU
#define AGGRID 2048   // agg: persistent, 8 blocks/CU, 32 waves/CU
#define AGWAVES (AGGRID*4)

typedef unsigned short u16;
typedef __attribute__((ext_vector_type(8))) short bf16x8;
typedef __attribute__((ext_vector_type(4))) float floatx4;

__device__ __forceinline__ float b2f(u16 h){ unsigned u=((unsigned)h)<<16; float f; __builtin_memcpy(&f,&u,4); return f; }
__device__ __forceinline__ u16 f2b(float f){ unsigned u; __builtin_memcpy(&u,&f,4); u = u + 0x7FFFu + ((u>>16)&1u); return (u16)(u>>16); }
__device__ __forceinline__ float siluf(float x){ return x*__builtin_amdgcn_rcpf(1.f+__expf(-x)); }
__device__ __forceinline__ float ldf(const void* p, long i, int isbf){
  return isbf ? b2f(((const u16*)p)[i]) : ((const float*)p)[i];
}
__device__ __forceinline__ float rdlane(float v, int l){
  int i; __builtin_memcpy(&i,&v,4);
  int r = __builtin_amdgcn_readlane(i, l);
  float f; __builtin_memcpy(&f,&r,4);
  return f;
}
// swizzled element offset for MFMA-internal N x 128 tensors (xb):
__device__ __forceinline__ long swz(long row, int col){
  return (row>>4)*2048 + (long)(((col>>4)*4 + (int)(row&3))*64 + (((int)(row&15))>>2)*16 + (col&15));
}

__global__ void detect_kernel(const void* lng, int* flag){
  if (threadIdx.x==0 && blockIdx.x==0) *flag = (((const u16*)lng)[0] != 0) ? 1 : 0;
}

// ---------- merged setup: phases partitioned by blockIdx ----------
#define SU_W12   192
#define SU_EBW   704
#define SU_W2P   708
#define SU_PPARM 712
#define SU_PROJ  713
#define SU_CVTP  25713
#define SU_END   26104
__global__ __launch_bounds__(256) void setup_kernel(
    const void* __restrict__ ew1, const void* __restrict__ ew2,
    const void* __restrict__ nw1, const void* __restrict__ nw2,
    u16* __restrict__ packed,
    const void* __restrict__ eb2, const void* __restrict__ pw1,
    const void* __restrict__ pb1, const void* __restrict__ pw2v, const void* __restrict__ pb2,
    float* __restrict__ w2p, float* __restrict__ c2p, float* __restrict__ pparm,
    float* __restrict__ ebW,
    const void* __restrict__ nf, const void* __restrict__ npw, const void* __restrict__ npb,
    u16* __restrict__ xb,
    const void* __restrict__ pos, float* __restrict__ pf,
    const int* __restrict__ flagp)
{
  const int isbf = *flagp;
  const int b = blockIdx.x, tid = threadIdx.x;
  __shared__ float red[128];
  if (b < SU_W12){
    int t = b*256 + tid;
    int m = t >> 11; int r = t & 2047;
    int lane = r & 63; int ntk = r >> 6;
    int kk = ntk >> 3, nt = ntk & 7;
    int l = m/6, w = m%6;
    const void* src; long off;
    switch(w){
      case 0: src=ew1; off=(long)l*257*128;            break; // W1a
      case 1: src=ew1; off=(long)l*257*128 + 128*128;  break; // W1b
      case 2: src=ew2; off=(long)l*128*128;            break; // EW2 (layout slot)
      case 3: src=nw1; off=(long)l*256*128;            break; // NW1a
      case 4: src=nw1; off=(long)l*256*128 + 128*128;  break; // NW1b (unused)
      default:src=nw2; off=(long)l*128*128;            break; // NW2
    }
    int c  = nt*16 + (lane & 15);
    int k0 = kk*32 + (lane >> 4)*8;
    u16 vals[8];
#pragma unroll
    for (int j=0;j<8;j++){
      long idx = off + (long)(k0+j)*128 + c;
      vals[j] = isbf ? ((const u16*)src)[idx] : f2b(((const float*)src)[idx]);
    }
    bf16x8 v; __builtin_memcpy(&v, vals, 16);
    *(bf16x8*)(packed + (long)t*8) = v;
  } else if (b < SU_EBW){
    int bb = b - SU_W12;
    int l = bb >> 7, k = bb & 127;
    if (tid < 128){
      int j = tid;
      long e2 = (long)l*16384 + (long)k*128;
      long nb = (long)l*256*128 + 128*128;
      float acc = 0.f;
      for (int d=0; d<128; d++)
        acc += ldf(ew2, e2 + d, isbf) * ldf(nw1, nb + (long)d*128 + j, isbf);
      int kk = k>>5, lane = ((k>>3)&3)*16 + (j&15), nt = j>>4, jj = k&7;
      packed[(long)(24+l)*16384 + (long)((kk*8+nt)*64 + lane)*8 + jj] = f2b(acc);
    }
  } else if (b < SU_W2P){
    int l = b - SU_EBW;
    if (tid < 128){
      int j = tid;
      long nb = (long)l*256*128 + 128*128;
      float acc = 0.f;
      for (int d=0; d<128; d++)
        acc += ldf(eb2, (long)l*128 + d, isbf) * ldf(nw1, nb + (long)d*128 + j, isbf);
      ebW[l*128+j] = acc;
    }
  } else if (b < SU_PPARM){
    int l = b - SU_W2P;
    int i = tid;
    long Woff = (long)l*128*128, poff = (long)l*129;
    if (i < 128){
      float acc = 0.f;
      for (int j=0;j<128;j++) acc += ldf(ew2, Woff + (long)i*128 + j, isbf) * ldf(pw1, poff + j, isbf);
      w2p[l*128+i] = acc;
      red[i] = ldf(eb2, (long)l*128 + i, isbf) * ldf(pw1, poff + i, isbf);
    }
    __syncthreads();
    for (int st=64; st>0; st>>=1){ if (i<st) red[i]+=red[i+st]; __syncthreads(); }
    if (i==0) c2p[l] = red[0];
  } else if (b == SU_PPARM){
    int l = tid;
    if (l < 4){
      pparm[l*4+0] = ldf(pw1, (long)l*129 + 128, isbf);
      pparm[l*4+1] = ldf(pb1, l, isbf);
      pparm[l*4+2] = ldf(pw2v, l, isbf);
      pparm[l*4+3] = ldf(pb2, l, isbf);
    }
  } else if (b < SU_CVTP){
    int n = (b - SU_PROJ)*2 + (tid>>7), d = tid & 127;
    if (n < NNODES){
      float acc = ldf(npb, d, isbf);
#pragma unroll
      for (int f=0; f<12; f++) acc += ldf(nf, (long)n*12+f, isbf) * ldf(npw, f*128+d, isbf);
      xb[swz(n, d)] = f2b(acc);   // swizzled residual layout
    }
  } else {
    int i = (b - SU_CVTP)*256 + tid;
    if (i < 2*NNODES) pf[i] = ldf(pos, i, isbf);
  }
}

// ---------- CSR build: histogram, 3-stage scan, scatter ----------
__global__ __launch_bounds__(256) void hist_kernel(const int* __restrict__ tgt, int* __restrict__ cnt, int E){
  int i = blockIdx.x*256 + threadIdx.x;
  if (i < E) atomicAdd(&cnt[tgt[i]], 1);
}

__global__ __launch_bounds__(256) void bsum_kernel(const int* __restrict__ cnt, int* __restrict__ bsum, int N){
  int i = blockIdx.x*256 + threadIdx.x;
  int v = (i < N) ? cnt[i] : 0;
#pragma unroll
  for (int off=32; off; off>>=1) v += __shfl_down(v, off);
  __shared__ int ws[4];
  if ((threadIdx.x & 63) == 0) ws[threadIdx.x>>6] = v;
  __syncthreads();
  if (threadIdx.x == 0) bsum[blockIdx.x] = ws[0]+ws[1]+ws[2]+ws[3];
}

__global__ __launch_bounds__(256) void bscan_kernel(int* __restrict__ bsum, int nb){
  __shared__ int lds[256];
  int i = threadIdx.x;
  int v = (i < nb) ? bsum[i] : 0;
  lds[i] = v; __syncthreads();
#pragma unroll
  for (int off=1; off<256; off<<=1){
    int t = (i>=off)? lds[i-off] : 0; __syncthreads();
    lds[i] += t; __syncthreads();
  }
  if (i < nb) bsum[i] = lds[i] - v;  // exclusive prefix
}

__global__ __launch_bounds__(256) void csr_kernel(
    const int* __restrict__ cnt, const int* __restrict__ bsum,
    int* __restrict__ rowptr, int* __restrict__ cursor, float* __restrict__ degf, int N)
{
  __shared__ int lds[256];
  int i = blockIdx.x*256 + threadIdx.x;
  int c = (i < N) ? cnt[i] : 0;
  lds[threadIdx.x] = c; __syncthreads();
#pragma unroll
  for (int off=1; off<256; off<<=1){
    int t = (threadIdx.x>=off)? lds[threadIdx.x-off] : 0; __syncthreads();
    lds[threadIdx.x] += t; __syncthreads();
  }
  int run = bsum[blockIdx.x] + lds[threadIdx.x] - c;  // exclusive
  if (i < N){
    rowptr[i] = run; cursor[i] = run; degf[i] = (float)c;
    if (i == N-1) rowptr[N] = run + c;
  }
}

__global__ __launch_bounds__(256) void scatter_kernel(
    const int* __restrict__ src, const int* __restrict__ tgt,
    int* __restrict__ cursor, int* __restrict__ permsrc, int E)
{
  int e = blockIdx.x*256 + threadIdx.x;
  if (e >= E) return;
  int t = tgt[e];
  int p = atomicAdd(&cursor[t], 1);
  permsrc[p] = src[e];
}

// ---------- single streaming matmul: Out = bf16(x@W [+ bias]) ----------
// X swizzled; W packed in LDS (32KB); Out row-major via per-wave 4KB LDS stage.
// LDS total 48KB -> 3 blocks/CU = 3 waves/SIMD.
__global__ __launch_bounds__(256, 3) void mm_single_kernel(
    const u16* __restrict__ X, const u16* __restrict__ W,
    const void* __restrict__ bias, long bias_off, int hasbias,
    u16* __restrict__ Out, const int* __restrict__ flagp)
{
  extern __shared__ u16 dls[];
  u16* wl = dls;                         // 16384 u16 = 32KB
  const int tid = threadIdx.x, wave = tid>>6, lane = tid&63;
  const int isbf = *flagp;
  const int lr = lane&15, lg = lane>>4;
  u16* sw = dls + 16384 + (wave<<11);    // per-wave 2048 u16 = 4KB
  for (int i=tid; i<2048; i+=256)
    *(bf16x8*)(wl + (long)i*8) = *(const bf16x8*)(W + (long)i*8);
  float biasv[8];
#pragma unroll
  for (int nt=0;nt<8;nt++) biasv[nt] = hasbias ? ldf(bias, bias_off + nt*16 + lr, isbf) : 0.f;
  int aoff[4];
#pragma unroll
  for (int kk=0;kk<4;kk++) aoff[kk] = ((2*kk + (lg>>1))*4 + (lr&3))*64 + (lr>>2)*16 + (lg&1)*8;
  __syncthreads();
  for (int tile = blockIdx.x*4 + wave; tile < NTILES; tile += SGRID*4){
    const u16* xt = X + (long)tile*2048;
    bf16x8 a[4];
#pragma unroll
    for (int kk=0;kk<4;kk++) a[kk] = *(const bf16x8*)(xt + aoff[kk]);
    floatx4 acc[8];
#pragma unroll
    for (int i=0;i<8;i++) acc[i]=(floatx4){0,0,0,0};
#pragma unroll
    for (int kk=0;kk<4;kk++){
#pragma unroll
      for (int nt=0;nt<8;nt++){
        bf16x8 b = *(const bf16x8*)(wl + ((kk*8+nt)*64 + lane)*8);
        acc[nt] = __builtin_amdgcn_mfma_f32_16x16x32_bf16(a[kk], b, acc[nt], 0, 0, 0);
      }
    }
    u16* ot = Out + (long)tile*2048;
#pragma unroll
    for (int r=0;r<4;r++){
#pragma unroll
      for (int nt=0;nt<8;nt++) sw[(lg*4+r)*128 + nt*16 + lr] = f2b(acc[nt][r] + biasv[nt]);
    }
#pragma unroll
    for (int j=0;j<4;j++){
      bf16x8 v = *(const bf16x8*)(sw + j*512 + lane*8);
      *(bf16x8*)(ot + j*512 + lane*8) = v;
    }
  }
}

// ---------- mega: h = silu(xb@NW1a + Hb@W12 + deg*ebW + nb1); res = xb + h@NW2 + nb2 ----------
// 512 threads, 8 waves. LDS: W1(32K) + W12(32K) + W2(32K) + 8x per-wave stage
// (2176 u16, row stride 136 = 272B, 16B-aligned) = 130KB -> 1 block/CU.
// h never touches HBM: C-frags -> LDS stage -> A-frags (per-wave, DS in-order).
// X and xb alias (same buffer, no __restrict__): each tile owned by one wave.
template<int LN>
__global__ __launch_bounds__(512, 2) void mega_kernel(
    const u16* X, const u16* __restrict__ H,
    const u16* __restrict__ W1, const u16* __restrict__ W12, const u16* __restrict__ W2,
    const void* __restrict__ nb1, long nb1_off,
    const void* __restrict__ nb2, long nb2_off,
    const float* __restrict__ degf, const float* __restrict__ ebW,
    u16* xb,
    const void* __restrict__ lng, const void* __restrict__ lnb, void* __restrict__ outp,
    const int* __restrict__ flagp)
{
  extern __shared__ u16 dls[];
  u16* w1s  = dls;
  u16* w12s = dls + 16384;
  u16* w2s  = dls + 32768;
  const int tid = threadIdx.x, wave = tid>>6, lane = tid&63;
  const int isbf = *flagp;
  const int lr = lane&15, lg = lane>>4;
  u16* stg = dls + 49152 + wave*2176;
  for (int i=tid; i<2048; i+=512){
    *(bf16x8*)(w1s  + (long)i*8) = *(const bf16x8*)(W1  + (long)i*8);
    *(bf16x8*)(w12s + (long)i*8) = *(const bf16x8*)(W12 + (long)i*8);
    *(bf16x8*)(w2s  + (long)i*8) = *(const bf16x8*)(W2  + (long)i*8);
  }
  float nb1v[8], nb2v[8], ebv[8];
#pragma unroll
  for (int nt=0;nt<8;nt++){
    int col = nt*16 + lr;
    nb1v[nt] = ldf(nb1, nb1_off + col, isbf);
    nb2v[nt] = ldf(nb2, nb2_off + col, isbf);
    ebv[nt]  = ebW[col];
  }
  float gv[8], bvv[8];
  if (LN){
#pragma unroll
    for (int nt=0;nt<8;nt++){ int col=nt*16+lr; gv[nt]=ldf(lng,col,isbf); bvv[nt]=ldf(lnb,col,isbf); }
  }
  int aoff[4];
#pragma unroll
  for (int kk=0;kk<4;kk++) aoff[kk] = ((2*kk + (lg>>1))*4 + (lr&3))*64 + (lr>>2)*16 + (lg&1)*8;
  __syncthreads();
  for (int tile = blockIdx.x*8 + wave; tile < NTILES; tile += MGRID*8){
    // ---- phase 1: hidden pre-activation ----
    const u16* xt = X + (long)tile*2048;
    const u16* hr = H + ((long)tile*16 + lr)*128;   // row-major Hb
    bf16x8 ax[4], ah[4];
#pragma unroll
    for (int kk=0;kk<4;kk++){
      ax[kk] = *(const bf16x8*)(xt + aoff[kk]);
      ah[kk] = *(const bf16x8*)(hr + kk*32 + lg*8);
    }
    floatx4 acc[8];
#pragma unroll
    for (int i=0;i<8;i++) acc[i]=(floatx4){0,0,0,0};
#pragma unroll
    for (int kk=0;kk<4;kk++){
#pragma unroll
      for (int nt=0;nt<8;nt++){
        bf16x8 b1 = *(const bf16x8*)(w1s + ((kk*8+nt)*64 + lane)*8);
        acc[nt] = __builtin_amdgcn_mfma_f32_16x16x32_bf16(ax[kk], b1, acc[nt], 0, 0, 0);
        bf16x8 b2 = *(const bf16x8*)(w12s + ((kk*8+nt)*64 + lane)*8);
        acc[nt] = __builtin_amdgcn_mfma_f32_16x16x32_bf16(ah[kk], b2, acc[nt], 0, 0, 0);
      }
    }
    float dv[4];
#pragma unroll
    for (int r=0;r<4;r++) dv[r] = degf[(long)tile*16 + lg*4 + r];
    // ---- stage h: C-frag -> row-major LDS (stride 136 = 272B, 16B aligned) ----
#pragma unroll
    for (int r=0;r<4;r++){
#pragma unroll
      for (int nt=0;nt<8;nt++)
        stg[(lg*4+r)*136 + nt*16 + lr] = f2b(siluf(acc[nt][r] + nb1v[nt] + dv[r]*ebv[nt]));
    }
    // ---- phase 2: h @ NW2 (A-frags from stage; per-wave DS in-order) ----
    bf16x8 ha[4];
#pragma unroll
    for (int kk=0;kk<4;kk++) ha[kk] = *(const bf16x8*)(stg + lr*136 + kk*32 + lg*8);
    floatx4 acc2[8];
#pragma unroll
    for (int i=0;i<8;i++) acc2[i]=(floatx4){0,0,0,0};
#pragma unroll
    for (int kk=0;kk<4;kk++){
#pragma unroll
      for (int nt=0;nt<8;nt++){
        bf16x8 b = *(const bf16x8*)(w2s + ((kk*8+nt)*64 + lane)*8);
        acc2[nt] = __builtin_amdgcn_mfma_f32_16x16x32_bf16(ha[kk], b, acc2[nt], 0, 0, 0);
      }
    }
    // ---- residual ----
    u16* xo = xb + (long)tile*2048;
#pragma unroll
    for (int r=0;r<4;r++){
#pragma unroll
      for (int nt=0;nt<8;nt++){
        int o = (nt*4+r)*64 + lane;           // full-line swizzled RMW
        float v = acc2[nt][r] + nb2v[nt] + b2f(xo[o]);
        acc2[nt][r] = v;
        if (!LN) xo[o] = f2b(v);
      }
    }
    if (LN){
      float s[4] = {0,0,0,0}, q[4] = {0,0,0,0};
#pragma unroll
      for (int r=0;r<4;r++){
#pragma unroll
        for (int nt=0;nt<8;nt++){ float v = acc2[nt][r]; s[r] += v; q[r] += v*v; }
      }
#pragma unroll
      for (int mask=1; mask<16; mask<<=1){
#pragma unroll
        for (int r=0;r<4;r++){ s[r] += __shfl_xor(s[r], mask); q[r] += __shfl_xor(q[r], mask); }
      }
      float mu4[4], inv4[4];
#pragma unroll
      for (int r=0;r<4;r++){
        float mu = s[r]*(1.f/128.f);
        float var = q[r]*(1.f/128.f) - mu*mu;
        mu4[r] = mu; inv4[r] = rsqrtf(var + 1e-5f);
      }
      if (isbf){
        // reuse stage (h frags already consumed) with 128-stride for contiguous rows
#pragma unroll
        for (int r=0;r<4;r++){
#pragma unroll
          for (int nt=0;nt<8;nt++)
            stg[(lg*4+r)*128 + nt*16 + lr] = f2b((acc2[nt][r]-mu4[r])*inv4[r]*gv[nt] + bvv[nt]);
        }
        u16* ot = (u16*)outp + (long)tile*2048;
#pragma unroll
        for (int j=0;j<4;j++){
          bf16x8 v = *(const bf16x8*)(stg + j*512 + lane*8);
          *(bf16x8*)(ot + j*512 + lane*8) = v;
        }
      } else {
#pragma unroll
        for (int r=0;r<4;r++){
          long row = (long)tile*16 + lg*4 + r;
#pragma unroll
          for (int nt=0;nt<8;nt++){
            int col = nt*16 + lr;
            ((float*)outp)[row*128+col] = (acc2[nt][r]-mu4[r])*inv4[r]*gv[nt] + bvv[nt];
          }
        }
      }
    }
  }
}

// ---------- CSR aggregation: persistent waves, 8-edge chunks, folded butterfly ----------
// A/B/Hb row-major. One wave per node (grid-stride). Lane group cc=lane&7 owns
// edge cc of the chunk (1x sqrt/exp/rcp/rcp per edge instead of 8x). Folded
// butterfly: per xor step keep/send half the values by own lane bit (all
// compile-time indices) -> 7 shfl + 7 add + ~14 cndmask vs 96 ops naive.
__global__ __launch_bounds__(256) void agg_kernel(
    const int* __restrict__ rowptr, const int* __restrict__ permsrc,
    const float* __restrict__ pf_in,
    const u16* __restrict__ A, const u16* __restrict__ B,
    const void* __restrict__ ew1, long w1c_off,
    const float* __restrict__ w2p, const float* __restrict__ c2pl,
    const float* __restrict__ pp,
    u16* __restrict__ Hb, float* __restrict__ pf_out, int N,
    const int* __restrict__ flagp)
{
  const int isbf = *flagp;
  int tid = threadIdx.x, lane = tid & 63;
  int wid = blockIdx.x*4 + (tid>>6);
  const int cc = lane & 7;
  const int b0 = lane & 1, b1 = lane & 2, b2 = lane & 4;
  // per-wave constants hoisted out of the node loop
  float c0 = ldf(ew1, w1c_off + 2*lane,     isbf);
  float c1 = ldf(ew1, w1c_off + 2*lane + 1, isbf);
  float2 wp = *(const float2*)(w2p + 2*lane);
  float c2 = c2pl[0];
  float p0 = pp[0], p1 = pp[1], p2 = pp[2], p3 = pp[3];
  for (int t = wid; t < N; t += AGWAVES){
    int tu = __builtin_amdgcn_readfirstlane(t);   // wave-uniform -> scalar loads
    int jb = rowptr[tu], je = rowptr[tu+1];
    float2 pt = *(const float2*)(pf_in + 2*(long)tu);
    unsigned bv = *(const unsigned*)(B + (long)tu*128 + 2*lane);
    float bb0 = b2f((u16)bv), bb1 = b2f((u16)(bv>>16));
    float h0a = 0.f, h1a = 0.f, dpx = 0.f, dpy = 0.f;
    for (int j0 = jb; j0 < je; j0 += 8){
      int m = je - j0; if (m > 8) m = 8;       // wave-uniform
      int s[8];
#pragma unroll
      for (int c=0;c<8;c++) s[c] = permsrc[j0 + (c<m ? c : 0)];
      // ---- packed scalar phase: lane group cc handles edge cc ----
      int scc = s[0];
#pragma unroll
      for (int c=1;c<8;c++) scc = (cc==c) ? s[c] : scc;
      float2 psc = *(const float2*)(pf_in + 2*(long)scc);
      float dxc = pt.x - psc.x, dyc = pt.y - psc.y;
      float ddc = __builtin_amdgcn_sqrtf(dxc*dxc + dyc*dyc);
      float dd_s[8];
#pragma unroll
      for (int c=0;c<8;c++) dd_s[c] = rdlane(ddc, c);   // lane c has cc==c
      // ---- column phase (required math, fully lane-utilized) ----
      unsigned av[8];
#pragma unroll
      for (int c=0;c<8;c++) if (c<m) av[c] = *(const unsigned*)(A + (long)s[c]*128 + 2*lane);
      float part[8];
#pragma unroll
      for (int c=0;c<8;c++){
        if (c<m){
          float h0 = siluf(b2f((u16)av[c])       + bb0 + dd_s[c]*c0);
          float h1 = siluf(b2f((u16)(av[c]>>16)) + bb1 + dd_s[c]*c1);
          h0a += h0; h1a += h1;
          part[c] = h0*wp.x + h1*wp.y;
        } else part[c] = 0.f;
      }
      // ---- folded butterfly: deliver full sum of part[c] to lanes with cc==c ----
      float u[4];
#pragma unroll
      for (int i=0;i<4;i++){
        float keep = b0 ? part[2*i+1] : part[2*i];
        float send = b0 ? part[2*i]   : part[2*i+1];
        u[i] = keep + __shfl_xor(send, 1);
      }
      float v2[2];
#pragma unroll
      for (int i=0;i<2;i++){
        float keep = b1 ? u[2*i+1] : u[2*i];
        float send = b1 ? u[2*i]   : u[2*i+1];
        v2[i] = keep + __shfl_xor(send, 2);
      }
      {
        float keep = b2 ? v2[1] : v2[0];
        float send = b2 ? v2[0] : v2[1];
        float w = keep + __shfl_xor(send, 4);
        w += __shfl_xor(w, 8);
        w += __shfl_xor(w, 16);
        w += __shfl_xor(w, 32);
        // ---- packed tail: pwv & pos contribution (1x trans each per edge) ----
        float sprec = w + c2 + ddc*p0 + p1;
        float pwvc  = siluf(sprec)*p2 + p3;
        float invc  = __builtin_amdgcn_rcpf(ddc + 1e-6f);
        if (cc < m){ dpx += dxc*invc*pwvc; dpy += dyc*invc*pwvc; }
      }
    }
    *(unsigned*)(Hb + (long)tu*128 + 2*lane) = (unsigned)f2b(h0a) | ((unsigned)f2b(h1a)<<16);
    // combine the 8 lane groups' dp partials
    dpx += __shfl_xor(dpx, 1); dpx += __shfl_xor(dpx, 2); dpx += __shfl_xor(dpx, 4);
    dpy += __shfl_xor(dpy, 1); dpy += __shfl_xor(dpy, 2); dpy += __shfl_xor(dpy, 4);
    if (lane == 0){
      float2 o; o.x = pt.x + dpx; o.y = pt.y + dpy;
      *(float2*)(pf_out + 2*(long)tu) = o;
    }
  }
}

extern "C" void kernel_launch(void* const* d_in, const int* in_sizes, int n_in,
                              void* d_out, int out_size, void* d_ws, size_t ws_size,
                              hipStream_t stream)
{
  const void* nf  = d_in[0];
  const void* pos = d_in[1];
  const void* npw = d_in[3];
  const void* npb = d_in[4];
  const void* ew1 = d_in[7];
  const void* eb1 = d_in[8];
  const void* ew2 = d_in[9];
  const void* eb2 = d_in[10];
  const void* nw1 = d_in[11];
  const void* nb1 = d_in[12];
  const void* nw2 = d_in[13];
  const void* nb2 = d_in[14];
  const void* pw1 = d_in[15];
  const void* pb1 = d_in[16];
  const void* pw2 = d_in[17];
  const void* pb2 = d_in[18];
  const void* lng = d_in[19];
  const void* lnb = d_in[20];
  const int* eidx = (const int*)d_in[21];
  const int N = NNODES, E = NEDGES;
  const int* srcp = eidx;
  const int* tgtp = eidx + E;

  char* w = (char*)d_ws;
  size_t off = 0;
  auto alloc = [&](size_t bytes)->char* { char* p = w + off; off += (bytes + 255)/256*256; return p; };
  u16*   xb    = (u16*)  alloc((size_t)N*128*2);
  u16*   Ab    = (u16*)  alloc((size_t)N*128*2);
  u16*   Bb    = (u16*)  alloc((size_t)N*128*2);
  u16*   Hb    = (u16*)  alloc((size_t)N*128*2);
  float* pf0   = (float*)alloc((size_t)N*2*4);
  float* pf1   = (float*)alloc((size_t)N*2*4);
  int*   cnt   = (int*)  alloc((size_t)N*4);
  int*   rowptr= (int*)  alloc((size_t)(N+1)*4);
  int*   cursor= (int*)  alloc((size_t)N*4);
  float* degf  = (float*)alloc((size_t)N*4);
  int*   perm  = (int*)  alloc((size_t)E*4);
  int*   bsum  = (int*)  alloc(256*4);
  u16*   pk    = (u16*)  alloc((size_t)28*16384*2);
  float* ebW   = (float*)alloc(4*128*4);
  float* w2p   = (float*)alloc(4*128*4);
  float* c2p   = (float*)alloc(4*4);
  float* pparm = (float*)alloc(16*4);
  int*   flag  = (int*)  alloc(4);

  const int NB = (N + 255)/256;  // 196 <= 256
  detect_kernel<<<1, 64, 0, stream>>>(lng, flag);
  hipMemsetAsync(cnt, 0, (size_t)N*4, stream);
  hist_kernel<<<(E+255)/256, 256, 0, stream>>>(tgtp, cnt, E);
  bsum_kernel<<<NB, 256, 0, stream>>>(cnt, bsum, N);
  bscan_kernel<<<1, 256, 0, stream>>>(bsum, NB);
  csr_kernel<<<NB, 256, 0, stream>>>(cnt, bsum, rowptr, cursor, degf, N);
  scatter_kernel<<<(E+255)/256, 256, 0, stream>>>(srcp, tgtp, cursor, perm, E);
  setup_kernel<<<SU_END, 256, 0, stream>>>(
      ew1, ew2, nw1, nw2, pk,
      eb2, pw1, pb1, pw2, pb2,
      w2p, c2p, pparm, ebW,
      nf, npw, npb, xb,
      pos, pf0, flag);

  // layer 0 A/B from projected x (split kernels: 48KB LDS -> 3 blocks/CU)
  mm_single_kernel<<<SGRID, 256, 49152, stream>>>(xb, pk + 0*16384, eb1, 0, 1, Ab, flag);
  mm_single_kernel<<<SGRID, 256, 49152, stream>>>(xb, pk + 1*16384, nullptr, 0, 0, Bb, flag);
  for (int l = 0; l < 4; l++){
    const u16* NW1a = pk + (l*6+3)*16384;
    const u16* NW2p = pk + (l*6+5)*16384;
    const u16* W12p = pk + (24+l)*16384;
    float* pin  = (l & 1) ? pf1 : pf0;
    float* pout = (l & 1) ? pf0 : pf1;

    agg_kernel<<<AGGRID, 256, 0, stream>>>(
        rowptr, perm, pin, Ab, Bb,
        ew1, (long)l*257*128 + 256*128,
        w2p + l*128, c2p + l, pparm + l*4,
        Hb, pout, N, flag);
    if (l < 3){
      mega_kernel<0><<<MGRID, 512, 133120, stream>>>(
          xb, Hb, NW1a, W12p, NW2p, nb1, (long)l*128, nb2, (long)l*128,
          degf, ebW + l*128, xb, nullptr, nullptr, nullptr, flag);
      mm_single_kernel<<<SGRID, 256, 49152, stream>>>(
          xb, pk + ((l+1)*6+0)*16384, eb1, (long)(l+1)*128, 1, Ab, flag);
      mm_single_kernel<<<SGRID, 256, 49152, stream>>>(
          xb, pk + ((l+1)*6+1)*16384, nullptr, 0, 0, Bb, flag);
    } else {
      mega_kernel<1><<<MGRID, 512, 133120, stream>>>(
          xb, Hb, NW1a, W12p, NW2p, nb1, (long)l*128, nb2, (long)l*128,
          degf, ebW + l*128, xb, lng, lnb, d_out, flag);
    }
  }
}

// Round 10
// 434.407 us; speedup vs baseline: 1.0340x; 1.0340x over previous
//
#include <hip/hip_runtime.h>
#include <hip/hip_bf16.h>

// EGNN encoder, N=50000, E=250000, D=128, L=4. bf16 inputs/output (verified R2).
// R3: CSR-by-tgt aggregation.  R4: 3-stage CSR scan.  R5: agg chunked x4.
// R7: weight-stationary streaming matmuls.  R10: bf16 residual stream.
// R11: merged setup kernel. 524us.
// R12 FAILED: cooperative front-end (+350us, occupancy-starved).
// R13 FAILED: 512-thr mm blocks (scattered-2B store amplification exposed).
// R14: fragment-swizzled internal tensors (agg regressed). 563us.
// R15: split layouts per consumer; mm C-tiles staged through per-wave LDS. 518us.
// R16/R17 FAILED: weights from L1/L2 -> write-streams evict weights from L2.
//     LESSON: weight reuse must live in LDS.
// R18: mm_ab -> 2x mm_single; mm_hidden+mm_res fused into mega. 459us.
// R19: agg packed-scalar + persistent waves. 446.6us (predicted -40, got -13).
// R20 NEUTRAL: folded butterfly + 8-edge chunks. 449.2us. VALU-op-count model
//     falsified twice -> agg is NOT VALU-bound. Remaining suspect: per-node
//     serial chain (rowptr->permsrc->pf->A->compute), ~4 chained latencies/node.
// R21: lane-per-edge upfront phase: ONE permsrc load + ONE pf gather + ONE
//     sqrt/rcp per node covers all edges (deg<=64; super-chunk loop for rare
//     overflow). Chunk loop gets s/dd via v_readlane (register-only) -> A-gather
//     addresses SGPR-ready early, chain depth 4+ -> 2. Butterfly delivery
//     (lane&7==c) matches lane-per-edge ownership exactly ((k0+c)&7==c).

#define NNODES 50000
#define NEDGES 250000
#define NTILES 3125   // 50000/16 exactly, no tail
#define SGRID  768    // mm_single: 768 blocks x 4 waves, 3 blocks/CU co-resident
#define MGRID  256    // mega: 256 blocks x 8 waves, 1 block/CU
#define AGGRID 2048   // agg: persistent, 8 blocks/CU, 32 waves/CU
#define AGWAVES (AGGRID*4)

typedef unsigned short u16;
typedef __attribute__((ext_vector_type(8))) short bf16x8;
typedef __attribute__((ext_vector_type(4))) float floatx4;

__device__ __forceinline__ float b2f(u16 h){ unsigned u=((unsigned)h)<<16; float f; __builtin_memcpy(&f,&u,4); return f; }
__device__ __forceinline__ u16 f2b(float f){ unsigned u; __builtin_memcpy(&u,&f,4); u = u + 0x7FFFu + ((u>>16)&1u); return (u16)(u>>16); }
__device__ __forceinline__ float siluf(float x){ return x*__builtin_amdgcn_rcpf(1.f+__expf(-x)); }
__device__ __forceinline__ float ldf(const void* p, long i, int isbf){
  return isbf ? b2f(((const u16*)p)[i]) : ((const float*)p)[i];
}
__device__ __forceinline__ float rdlane(float v, int l){
  int i; __builtin_memcpy(&i,&v,4);
  int r = __builtin_amdgcn_readlane(i, l);
  float f; __builtin_memcpy(&f,&r,4);
  return f;
}
// swizzled element offset for MFMA-internal N x 128 tensors (xb):
__device__ __forceinline__ long swz(long row, int col){
  return (row>>4)*2048 + (long)(((col>>4)*4 + (int)(row&3))*64 + (((int)(row&15))>>2)*16 + (col&15));
}

__global__ void detect_kernel(const void* lng, int* flag){
  if (threadIdx.x==0 && blockIdx.x==0) *flag = (((const u16*)lng)[0] != 0) ? 1 : 0;
}

// ---------- merged setup: phases partitioned by blockIdx ----------
#define SU_W12   192
#define SU_EBW   704
#define SU_W2P   708
#define SU_PPARM 712
#define SU_PROJ  713
#define SU_CVTP  25713
#define SU_END   26104
__global__ __launch_bounds__(256) void setup_kernel(
    const void* __restrict__ ew1, const void* __restrict__ ew2,
    const void* __restrict__ nw1, const void* __restrict__ nw2,
    u16* __restrict__ packed,
    const void* __restrict__ eb2, const void* __restrict__ pw1,
    const void* __restrict__ pb1, const void* __restrict__ pw2v, const void* __restrict__ pb2,
    float* __restrict__ w2p, float* __restrict__ c2p, float* __restrict__ pparm,
    float* __restrict__ ebW,
    const void* __restrict__ nf, const void* __restrict__ npw, const void* __restrict__ npb,
    u16* __restrict__ xb,
    const void* __restrict__ pos, float* __restrict__ pf,
    const int* __restrict__ flagp)
{
  const int isbf = *flagp;
  const int b = blockIdx.x, tid = threadIdx.x;
  __shared__ float red[128];
  if (b < SU_W12){
    int t = b*256 + tid;
    int m = t >> 11; int r = t & 2047;
    int lane = r & 63; int ntk = r >> 6;
    int kk = ntk >> 3, nt = ntk & 7;
    int l = m/6, w = m%6;
    const void* src; long off;
    switch(w){
      case 0: src=ew1; off=(long)l*257*128;            break; // W1a
      case 1: src=ew1; off=(long)l*257*128 + 128*128;  break; // W1b
      case 2: src=ew2; off=(long)l*128*128;            break; // EW2 (layout slot)
      case 3: src=nw1; off=(long)l*256*128;            break; // NW1a
      case 4: src=nw1; off=(long)l*256*128 + 128*128;  break; // NW1b (unused)
      default:src=nw2; off=(long)l*128*128;            break; // NW2
    }
    int c  = nt*16 + (lane & 15);
    int k0 = kk*32 + (lane >> 4)*8;
    u16 vals[8];
#pragma unroll
    for (int j=0;j<8;j++){
      long idx = off + (long)(k0+j)*128 + c;
      vals[j] = isbf ? ((const u16*)src)[idx] : f2b(((const float*)src)[idx]);
    }
    bf16x8 v; __builtin_memcpy(&v, vals, 16);
    *(bf16x8*)(packed + (long)t*8) = v;
  } else if (b < SU_EBW){
    int bb = b - SU_W12;
    int l = bb >> 7, k = bb & 127;
    if (tid < 128){
      int j = tid;
      long e2 = (long)l*16384 + (long)k*128;
      long nb = (long)l*256*128 + 128*128;
      float acc = 0.f;
      for (int d=0; d<128; d++)
        acc += ldf(ew2, e2 + d, isbf) * ldf(nw1, nb + (long)d*128 + j, isbf);
      int kk = k>>5, lane = ((k>>3)&3)*16 + (j&15), nt = j>>4, jj = k&7;
      packed[(long)(24+l)*16384 + (long)((kk*8+nt)*64 + lane)*8 + jj] = f2b(acc);
    }
  } else if (b < SU_W2P){
    int l = b - SU_EBW;
    if (tid < 128){
      int j = tid;
      long nb = (long)l*256*128 + 128*128;
      float acc = 0.f;
      for (int d=0; d<128; d++)
        acc += ldf(eb2, (long)l*128 + d, isbf) * ldf(nw1, nb + (long)d*128 + j, isbf);
      ebW[l*128+j] = acc;
    }
  } else if (b < SU_PPARM){
    int l = b - SU_W2P;
    int i = tid;
    long Woff = (long)l*128*128, poff = (long)l*129;
    if (i < 128){
      float acc = 0.f;
      for (int j=0;j<128;j++) acc += ldf(ew2, Woff + (long)i*128 + j, isbf) * ldf(pw1, poff + j, isbf);
      w2p[l*128+i] = acc;
      red[i] = ldf(eb2, (long)l*128 + i, isbf) * ldf(pw1, poff + i, isbf);
    }
    __syncthreads();
    for (int st=64; st>0; st>>=1){ if (i<st) red[i]+=red[i+st]; __syncthreads(); }
    if (i==0) c2p[l] = red[0];
  } else if (b == SU_PPARM){
    int l = tid;
    if (l < 4){
      pparm[l*4+0] = ldf(pw1, (long)l*129 + 128, isbf);
      pparm[l*4+1] = ldf(pb1, l, isbf);
      pparm[l*4+2] = ldf(pw2v, l, isbf);
      pparm[l*4+3] = ldf(pb2, l, isbf);
    }
  } else if (b < SU_CVTP){
    int n = (b - SU_PROJ)*2 + (tid>>7), d = tid & 127;
    if (n < NNODES){
      float acc = ldf(npb, d, isbf);
#pragma unroll
      for (int f=0; f<12; f++) acc += ldf(nf, (long)n*12+f, isbf) * ldf(npw, f*128+d, isbf);
      xb[swz(n, d)] = f2b(acc);   // swizzled residual layout
    }
  } else {
    int i = (b - SU_CVTP)*256 + tid;
    if (i < 2*NNODES) pf[i] = ldf(pos, i, isbf);
  }
}

// ---------- CSR build: histogram, 3-stage scan, scatter ----------
__global__ __launch_bounds__(256) void hist_kernel(const int* __restrict__ tgt, int* __restrict__ cnt, int E){
  int i = blockIdx.x*256 + threadIdx.x;
  if (i < E) atomicAdd(&cnt[tgt[i]], 1);
}

__global__ __launch_bounds__(256) void bsum_kernel(const int* __restrict__ cnt, int* __restrict__ bsum, int N){
  int i = blockIdx.x*256 + threadIdx.x;
  int v = (i < N) ? cnt[i] : 0;
#pragma unroll
  for (int off=32; off; off>>=1) v += __shfl_down(v, off);
  __shared__ int ws[4];
  if ((threadIdx.x & 63) == 0) ws[threadIdx.x>>6] = v;
  __syncthreads();
  if (threadIdx.x == 0) bsum[blockIdx.x] = ws[0]+ws[1]+ws[2]+ws[3];
}

__global__ __launch_bounds__(256) void bscan_kernel(int* __restrict__ bsum, int nb){
  __shared__ int lds[256];
  int i = threadIdx.x;
  int v = (i < nb) ? bsum[i] : 0;
  lds[i] = v; __syncthreads();
#pragma unroll
  for (int off=1; off<256; off<<=1){
    int t = (i>=off)? lds[i-off] : 0; __syncthreads();
    lds[i] += t; __syncthreads();
  }
  if (i < nb) bsum[i] = lds[i] - v;  // exclusive prefix
}

__global__ __launch_bounds__(256) void csr_kernel(
    const int* __restrict__ cnt, const int* __restrict__ bsum,
    int* __restrict__ rowptr, int* __restrict__ cursor, float* __restrict__ degf, int N)
{
  __shared__ int lds[256];
  int i = blockIdx.x*256 + threadIdx.x;
  int c = (i < N) ? cnt[i] : 0;
  lds[threadIdx.x] = c; __syncthreads();
#pragma unroll
  for (int off=1; off<256; off<<=1){
    int t = (threadIdx.x>=off)? lds[threadIdx.x-off] : 0; __syncthreads();
    lds[threadIdx.x] += t; __syncthreads();
  }
  int run = bsum[blockIdx.x] + lds[threadIdx.x] - c;  // exclusive
  if (i < N){
    rowptr[i] = run; cursor[i] = run; degf[i] = (float)c;
    if (i == N-1) rowptr[N] = run + c;
  }
}

__global__ __launch_bounds__(256) void scatter_kernel(
    const int* __restrict__ src, const int* __restrict__ tgt,
    int* __restrict__ cursor, int* __restrict__ permsrc, int E)
{
  int e = blockIdx.x*256 + threadIdx.x;
  if (e >= E) return;
  int t = tgt[e];
  int p = atomicAdd(&cursor[t], 1);
  permsrc[p] = src[e];
}

// ---------- single streaming matmul: Out = bf16(x@W [+ bias]) ----------
// X swizzled; W packed in LDS (32KB); Out row-major via per-wave 4KB LDS stage.
// LDS total 48KB -> 3 blocks/CU = 3 waves/SIMD.
__global__ __launch_bounds__(256, 3) void mm_single_kernel(
    const u16* __restrict__ X, const u16* __restrict__ W,
    const void* __restrict__ bias, long bias_off, int hasbias,
    u16* __restrict__ Out, const int* __restrict__ flagp)
{
  extern __shared__ u16 dls[];
  u16* wl = dls;                         // 16384 u16 = 32KB
  const int tid = threadIdx.x, wave = tid>>6, lane = tid&63;
  const int isbf = *flagp;
  const int lr = lane&15, lg = lane>>4;
  u16* sw = dls + 16384 + (wave<<11);    // per-wave 2048 u16 = 4KB
  for (int i=tid; i<2048; i+=256)
    *(bf16x8*)(wl + (long)i*8) = *(const bf16x8*)(W + (long)i*8);
  float biasv[8];
#pragma unroll
  for (int nt=0;nt<8;nt++) biasv[nt] = hasbias ? ldf(bias, bias_off + nt*16 + lr, isbf) : 0.f;
  int aoff[4];
#pragma unroll
  for (int kk=0;kk<4;kk++) aoff[kk] = ((2*kk + (lg>>1))*4 + (lr&3))*64 + (lr>>2)*16 + (lg&1)*8;
  __syncthreads();
  for (int tile = blockIdx.x*4 + wave; tile < NTILES; tile += SGRID*4){
    const u16* xt = X + (long)tile*2048;
    bf16x8 a[4];
#pragma unroll
    for (int kk=0;kk<4;kk++) a[kk] = *(const bf16x8*)(xt + aoff[kk]);
    floatx4 acc[8];
#pragma unroll
    for (int i=0;i<8;i++) acc[i]=(floatx4){0,0,0,0};
#pragma unroll
    for (int kk=0;kk<4;kk++){
#pragma unroll
      for (int nt=0;nt<8;nt++){
        bf16x8 b = *(const bf16x8*)(wl + ((kk*8+nt)*64 + lane)*8);
        acc[nt] = __builtin_amdgcn_mfma_f32_16x16x32_bf16(a[kk], b, acc[nt], 0, 0, 0);
      }
    }
    u16* ot = Out + (long)tile*2048;
#pragma unroll
    for (int r=0;r<4;r++){
#pragma unroll
      for (int nt=0;nt<8;nt++) sw[(lg*4+r)*128 + nt*16 + lr] = f2b(acc[nt][r] + biasv[nt]);
    }
#pragma unroll
    for (int j=0;j<4;j++){
      bf16x8 v = *(const bf16x8*)(sw + j*512 + lane*8);
      *(bf16x8*)(ot + j*512 + lane*8) = v;
    }
  }
}

// ---------- mega: h = silu(xb@NW1a + Hb@W12 + deg*ebW + nb1); res = xb + h@NW2 + nb2 ----------
// 512 threads, 8 waves. LDS: W1(32K) + W12(32K) + W2(32K) + 8x per-wave stage
// (2176 u16, row stride 136 = 272B, 16B-aligned) = 130KB -> 1 block/CU.
// h never touches HBM: C-frags -> LDS stage -> A-frags (per-wave, DS in-order).
// X and xb alias (same buffer, no __restrict__): each tile owned by one wave.
template<int LN>
__global__ __launch_bounds__(512, 2) void mega_kernel(
    const u16* X, const u16* __restrict__ H,
    const u16* __restrict__ W1, const u16* __restrict__ W12, const u16* __restrict__ W2,
    const void* __restrict__ nb1, long nb1_off,
    const void* __restrict__ nb2, long nb2_off,
    const float* __restrict__ degf, const float* __restrict__ ebW,
    u16* xb,
    const void* __restrict__ lng, const void* __restrict__ lnb, void* __restrict__ outp,
    const int* __restrict__ flagp)
{
  extern __shared__ u16 dls[];
  u16* w1s  = dls;
  u16* w12s = dls + 16384;
  u16* w2s  = dls + 32768;
  const int tid = threadIdx.x, wave = tid>>6, lane = tid&63;
  const int isbf = *flagp;
  const int lr = lane&15, lg = lane>>4;
  u16* stg = dls + 49152 + wave*2176;
  for (int i=tid; i<2048; i+=512){
    *(bf16x8*)(w1s  + (long)i*8) = *(const bf16x8*)(W1  + (long)i*8);
    *(bf16x8*)(w12s + (long)i*8) = *(const bf16x8*)(W12 + (long)i*8);
    *(bf16x8*)(w2s  + (long)i*8) = *(const bf16x8*)(W2  + (long)i*8);
  }
  float nb1v[8], nb2v[8], ebv[8];
#pragma unroll
  for (int nt=0;nt<8;nt++){
    int col = nt*16 + lr;
    nb1v[nt] = ldf(nb1, nb1_off + col, isbf);
    nb2v[nt] = ldf(nb2, nb2_off + col, isbf);
    ebv[nt]  = ebW[col];
  }
  float gv[8], bvv[8];
  if (LN){
#pragma unroll
    for (int nt=0;nt<8;nt++){ int col=nt*16+lr; gv[nt]=ldf(lng,col,isbf); bvv[nt]=ldf(lnb,col,isbf); }
  }
  int aoff[4];
#pragma unroll
  for (int kk=0;kk<4;kk++) aoff[kk] = ((2*kk + (lg>>1))*4 + (lr&3))*64 + (lr>>2)*16 + (lg&1)*8;
  __syncthreads();
  for (int tile = blockIdx.x*8 + wave; tile < NTILES; tile += MGRID*8){
    // ---- phase 1: hidden pre-activation ----
    const u16* xt = X + (long)tile*2048;
    const u16* hr = H + ((long)tile*16 + lr)*128;   // row-major Hb
    bf16x8 ax[4], ah[4];
#pragma unroll
    for (int kk=0;kk<4;kk++){
      ax[kk] = *(const bf16x8*)(xt + aoff[kk]);
      ah[kk] = *(const bf16x8*)(hr + kk*32 + lg*8);
    }
    floatx4 acc[8];
#pragma unroll
    for (int i=0;i<8;i++) acc[i]=(floatx4){0,0,0,0};
#pragma unroll
    for (int kk=0;kk<4;kk++){
#pragma unroll
      for (int nt=0;nt<8;nt++){
        bf16x8 b1 = *(const bf16x8*)(w1s + ((kk*8+nt)*64 + lane)*8);
        acc[nt] = __builtin_amdgcn_mfma_f32_16x16x32_bf16(ax[kk], b1, acc[nt], 0, 0, 0);
        bf16x8 b2 = *(const bf16x8*)(w12s + ((kk*8+nt)*64 + lane)*8);
        acc[nt] = __builtin_amdgcn_mfma_f32_16x16x32_bf16(ah[kk], b2, acc[nt], 0, 0, 0);
      }
    }
    float dv[4];
#pragma unroll
    for (int r=0;r<4;r++) dv[r] = degf[(long)tile*16 + lg*4 + r];
    // ---- stage h: C-frag -> row-major LDS (stride 136 = 272B, 16B aligned) ----
#pragma unroll
    for (int r=0;r<4;r++){
#pragma unroll
      for (int nt=0;nt<8;nt++)
        stg[(lg*4+r)*136 + nt*16 + lr] = f2b(siluf(acc[nt][r] + nb1v[nt] + dv[r]*ebv[nt]));
    }
    // ---- phase 2: h @ NW2 (A-frags from stage; per-wave DS in-order) ----
    bf16x8 ha[4];
#pragma unroll
    for (int kk=0;kk<4;kk++) ha[kk] = *(const bf16x8*)(stg + lr*136 + kk*32 + lg*8);
    floatx4 acc2[8];
#pragma unroll
    for (int i=0;i<8;i++) acc2[i]=(floatx4){0,0,0,0};
#pragma unroll
    for (int kk=0;kk<4;kk++){
#pragma unroll
      for (int nt=0;nt<8;nt++){
        bf16x8 b = *(const bf16x8*)(w2s + ((kk*8+nt)*64 + lane)*8);
        acc2[nt] = __builtin_amdgcn_mfma_f32_16x16x32_bf16(ha[kk], b, acc2[nt], 0, 0, 0);
      }
    }
    // ---- residual ----
    u16* xo = xb + (long)tile*2048;
#pragma unroll
    for (int r=0;r<4;r++){
#pragma unroll
      for (int nt=0;nt<8;nt++){
        int o = (nt*4+r)*64 + lane;           // full-line swizzled RMW
        float v = acc2[nt][r] + nb2v[nt] + b2f(xo[o]);
        acc2[nt][r] = v;
        if (!LN) xo[o] = f2b(v);
      }
    }
    if (LN){
      float s[4] = {0,0,0,0}, q[4] = {0,0,0,0};
#pragma unroll
      for (int r=0;r<4;r++){
#pragma unroll
        for (int nt=0;nt<8;nt++){ float v = acc2[nt][r]; s[r] += v; q[r] += v*v; }
      }
#pragma unroll
      for (int mask=1; mask<16; mask<<=1){
#pragma unroll
        for (int r=0;r<4;r++){ s[r] += __shfl_xor(s[r], mask); q[r] += __shfl_xor(q[r], mask); }
      }
      float mu4[4], inv4[4];
#pragma unroll
      for (int r=0;r<4;r++){
        float mu = s[r]*(1.f/128.f);
        float var = q[r]*(1.f/128.f) - mu*mu;
        mu4[r] = mu; inv4[r] = rsqrtf(var + 1e-5f);
      }
      if (isbf){
        // reuse stage (h frags already consumed) with 128-stride for contiguous rows
#pragma unroll
        for (int r=0;r<4;r++){
#pragma unroll
          for (int nt=0;nt<8;nt++)
            stg[(lg*4+r)*128 + nt*16 + lr] = f2b((acc2[nt][r]-mu4[r])*inv4[r]*gv[nt] + bvv[nt]);
        }
        u16* ot = (u16*)outp + (long)tile*2048;
#pragma unroll
        for (int j=0;j<4;j++){
          bf16x8 v = *(const bf16x8*)(stg + j*512 + lane*8);
          *(bf16x8*)(ot + j*512 + lane*8) = v;
        }
      } else {
#pragma unroll
        for (int r=0;r<4;r++){
          long row = (long)tile*16 + lg*4 + r;
#pragma unroll
          for (int nt=0;nt<8;nt++){
            int col = nt*16 + lr;
            ((float*)outp)[row*128+col] = (acc2[nt][r]-mu4[r])*inv4[r]*gv[nt] + bvv[nt];
          }
        }
      }
    }
  }
}

// ---------- CSR aggregation: lane-per-edge upfront phase + folded butterfly ----------
// A/B/Hb row-major. One wave per node (grid-stride, persistent). Upfront: lane L
// owns edge L (deg<=64/super-chunk): ONE permsrc load + ONE pf gather + ONE
// sqrt/rcp per node. Chunk loop gets s/dd via v_readlane (register-only), so
// A-gather addresses are SGPR-ready early and overlap previous chunk's compute.
__global__ __launch_bounds__(256) void agg_kernel(
    const int* __restrict__ rowptr, const int* __restrict__ permsrc,
    const float* __restrict__ pf_in,
    const u16* __restrict__ A, const u16* __restrict__ B,
    const void* __restrict__ ew1, long w1c_off,
    const float* __restrict__ w2p, const float* __restrict__ c2pl,
    const float* __restrict__ pp,
    u16* __restrict__ Hb, float* __restrict__ pf_out, int N,
    const int* __restrict__ flagp)
{
  const int isbf = *flagp;
  int tid = threadIdx.x, lane = tid & 63;
  int wid = blockIdx.x*4 + (tid>>6);
  const int b0 = lane & 1, b1 = lane & 2, b2 = lane & 4;
  // per-wave constants hoisted out of the node loop
  float c0 = ldf(ew1, w1c_off + 2*lane,     isbf);
  float c1 = ldf(ew1, w1c_off + 2*lane + 1, isbf);
  float2 wp = *(const float2*)(w2p + 2*lane);
  float c2 = c2pl[0];
  float p0 = pp[0], p1 = pp[1], p2 = pp[2], p3 = pp[3];
  for (int t = wid; t < N; t += AGWAVES){
    int tu = __builtin_amdgcn_readfirstlane(t);   // wave-uniform -> scalar loads
    int jb = rowptr[tu], je = rowptr[tu+1];
    int deg = je - jb;
    float2 pt = *(const float2*)(pf_in + 2*(long)tu);
    unsigned bv = *(const unsigned*)(B + (long)tu*128 + 2*lane);
    float bb0 = b2f((u16)bv), bb1 = b2f((u16)(bv>>16));
    float h0a = 0.f, h1a = 0.f, dpx = 0.f, dpy = 0.f;
    for (int e0 = 0; e0 < deg; e0 += 64){
      int nd = deg - e0; if (nd > 64) nd = 64;   // wave-uniform
      // ---- upfront lane-per-edge phase: 2 loads + 1 sqrt + 1 rcp per node ----
      int sl = permsrc[jb + e0 + (lane < nd ? lane : 0)];
      float2 psl = *(const float2*)(pf_in + 2*(long)sl);
      float dxl = pt.x - psl.x, dyl = pt.y - psl.y;
      float ddl = __builtin_amdgcn_sqrtf(dxl*dxl + dyl*dyl);
      float invl = __builtin_amdgcn_rcpf(ddl + 1e-6f);
      for (int k0 = 0; k0 < nd; k0 += 8){
        int m = nd - k0; if (m > 8) m = 8;       // wave-uniform
        // register-only broadcasts (no memory in the chain)
        int s_s[8]; float dd_s[8];
#pragma unroll
        for (int c=0;c<8;c++){
          s_s[c]  = __builtin_amdgcn_readlane(sl, k0+c);
          dd_s[c] = rdlane(ddl, k0+c);
        }
        // A gathers: SGPR base + lane offset, issue early, overlap compute
        unsigned av[8];
#pragma unroll
        for (int c=0;c<8;c++) if (c<m) av[c] = *(const unsigned*)(A + (long)s_s[c]*128 + 2*lane);
        float part[8];
#pragma unroll
        for (int c=0;c<8;c++){
          if (c<m){
            float h0 = siluf(b2f((u16)av[c])       + bb0 + dd_s[c]*c0);
            float h1 = siluf(b2f((u16)(av[c]>>16)) + bb1 + dd_s[c]*c1);
            h0a += h0; h1a += h1;
            part[c] = h0*wp.x + h1*wp.y;
          } else part[c] = 0.f;
        }
        // ---- folded butterfly: sum(part[c]) -> lanes with lane&7 == c ----
        float u[4];
#pragma unroll
        for (int i=0;i<4;i++){
          float keep = b0 ? part[2*i+1] : part[2*i];
          float send = b0 ? part[2*i]   : part[2*i+1];
          u[i] = keep + __shfl_xor(send, 1);
        }
        float v2[2];
#pragma unroll
        for (int i=0;i<2;i++){
          float keep = b1 ? u[2*i+1] : u[2*i];
          float send = b1 ? u[2*i]   : u[2*i+1];
          v2[i] = keep + __shfl_xor(send, 2);
        }
        float keep = b2 ? v2[1] : v2[0];
        float send = b2 ? v2[0] : v2[1];
        float w = keep + __shfl_xor(send, 4);
        w += __shfl_xor(w, 8);
        w += __shfl_xor(w, 16);
        w += __shfl_xor(w, 32);
        // ---- tail: lane k0+c owns edge e0+k0+c and received its sum ----
        if ((lane >> 3) == (k0 >> 3) && (lane & 7) < m){
          float sprec = w + c2 + ddl*p0 + p1;
          float pwvc  = siluf(sprec)*p2 + p3;
          dpx += dxl*invl*pwvc; dpy += dyl*invl*pwvc;
        }
      }
    }
    *(unsigned*)(Hb + (long)tu*128 + 2*lane) = (unsigned)f2b(h0a) | ((unsigned)f2b(h1a)<<16);
    // combine dp partials across all 64 lanes
    dpx += __shfl_xor(dpx, 1); dpx += __shfl_xor(dpx, 2); dpx += __shfl_xor(dpx, 4);
    dpx += __shfl_xor(dpx, 8); dpx += __shfl_xor(dpx, 16); dpx += __shfl_xor(dpx, 32);
    dpy += __shfl_xor(dpy, 1); dpy += __shfl_xor(dpy, 2); dpy += __shfl_xor(dpy, 4);
    dpy += __shfl_xor(dpy, 8); dpy += __shfl_xor(dpy, 16); dpy += __shfl_xor(dpy, 32);
    if (lane == 0){
      float2 o; o.x = pt.x + dpx; o.y = pt.y + dpy;
      *(float2*)(pf_out + 2*(long)tu) = o;
    }
  }
}

extern "C" void kernel_launch(void* const* d_in, const int* in_sizes, int n_in,
                              void* d_out, int out_size, void* d_ws, size_t ws_size,
                              hipStream_t stream)
{
  const void* nf  = d_in[0];
  const void* pos = d_in[1];
  const void* npw = d_in[3];
  const void* npb = d_in[4];
  const void* ew1 = d_in[7];
  const void* eb1 = d_in[8];
  const void* ew2 = d_in[9];
  const void* eb2 = d_in[10];
  const void* nw1 = d_in[11];
  const void* nb1 = d_in[12];
  const void* nw2 = d_in[13];
  const void* nb2 = d_in[14];
  const void* pw1 = d_in[15];
  const void* pb1 = d_in[16];
  const void* pw2 = d_in[17];
  const void* pb2 = d_in[18];
  const void* lng = d_in[19];
  const void* lnb = d_in[20];
  const int* eidx = (const int*)d_in[21];
  const int N = NNODES, E = NEDGES;
  const int* srcp = eidx;
  const int* tgtp = eidx + E;

  char* w = (char*)d_ws;
  size_t off = 0;
  auto alloc = [&](size_t bytes)->char* { char* p = w + off; off += (bytes + 255)/256*256; return p; };
  u16*   xb    = (u16*)  alloc((size_t)N*128*2);
  u16*   Ab    = (u16*)  alloc((size_t)N*128*2);
  u16*   Bb    = (u16*)  alloc((size_t)N*128*2);
  u16*   Hb    = (u16*)  alloc((size_t)N*128*2);
  float* pf0   = (float*)alloc((size_t)N*2*4);
  float* pf1   = (float*)alloc((size_t)N*2*4);
  int*   cnt   = (int*)  alloc((size_t)N*4);
  int*   rowptr= (int*)  alloc((size_t)(N+1)*4);
  int*   cursor= (int*)  alloc((size_t)N*4);
  float* degf  = (float*)alloc((size_t)N*4);
  int*   perm  = (int*)  alloc((size_t)E*4);
  int*   bsum  = (int*)  alloc(256*4);
  u16*   pk    = (u16*)  alloc((size_t)28*16384*2);
  float* ebW   = (float*)alloc(4*128*4);
  float* w2p   = (float*)alloc(4*128*4);
  float* c2p   = (float*)alloc(4*4);
  float* pparm = (float*)alloc(16*4);
  int*   flag  = (int*)  alloc(4);

  const int NB = (N + 255)/256;  // 196 <= 256
  detect_kernel<<<1, 64, 0, stream>>>(lng, flag);
  hipMemsetAsync(cnt, 0, (size_t)N*4, stream);
  hist_kernel<<<(E+255)/256, 256, 0, stream>>>(tgtp, cnt, E);
  bsum_kernel<<<NB, 256, 0, stream>>>(cnt, bsum, N);
  bscan_kernel<<<1, 256, 0, stream>>>(bsum, NB);
  csr_kernel<<<NB, 256, 0, stream>>>(cnt, bsum, rowptr, cursor, degf, N);
  scatter_kernel<<<(E+255)/256, 256, 0, stream>>>(srcp, tgtp, cursor, perm, E);
  setup_kernel<<<SU_END, 256, 0, stream>>>(
      ew1, ew2, nw1, nw2, pk,
      eb2, pw1, pb1, pw2, pb2,
      w2p, c2p, pparm, ebW,
      nf, npw, npb, xb,
      pos, pf0, flag);

  // layer 0 A/B from projected x (split kernels: 48KB LDS -> 3 blocks/CU)
  mm_single_kernel<<<SGRID, 256, 49152, stream>>>(xb, pk + 0*16384, eb1, 0, 1, Ab, flag);
  mm_single_kernel<<<SGRID, 256, 49152, stream>>>(xb, pk + 1*16384, nullptr, 0, 0, Bb, flag);
  for (int l = 0; l < 4; l++){
    const u16* NW1a = pk + (l*6+3)*16384;
    const u16* NW2p = pk + (l*6+5)*16384;
    const u16* W12p = pk + (24+l)*16384;
    float* pin  = (l & 1) ? pf1 : pf0;
    float* pout = (l & 1) ? pf0 : pf1;

    agg_kernel<<<AGGRID, 256, 0, stream>>>(
        rowptr, perm, pin, Ab, Bb,
        ew1, (long)l*257*128 + 256*128,
        w2p + l*128, c2p + l, pparm + l*4,
        Hb, pout, N, flag);
    if (l < 3){
      mega_kernel<0><<<MGRID, 512, 133120, stream>>>(
          xb, Hb, NW1a, W12p, NW2p, nb1, (long)l*128, nb2, (long)l*128,
          degf, ebW + l*128, xb, nullptr, nullptr, nullptr, flag);
      mm_single_kernel<<<SGRID, 256, 49152, stream>>>(
          xb, pk + ((l+1)*6+0)*16384, eb1, (long)(l+1)*128, 1, Ab, flag);
      mm_single_kernel<<<SGRID, 256, 49152, stream>>>(
          xb, pk + ((l+1)*6+1)*16384, nullptr, 0, 0, Bb, flag);
    } else {
      mega_kernel<1><<<MGRID, 512, 133120, stream>>>(
          xb, Hb, NW1a, W12p, NW2p, nb1, (long)l*128, nb2, (long)l*128,
          degf, ebW + l*128, xb, lng, lnb, d_out, flag);
    }
  }
}